// Round 6
// baseline (296.698 us; speedup 1.0000x reference)
//
#include <hip/hip_runtime.h>
#include <hip/hip_cooperative_groups.h>

namespace cg = cooperative_groups;

#define TBL_BITS 18
#define TBL_SIZE (1u << TBL_BITS)
#define TBL_MASK (TBL_SIZE - 1u)

// Grid geometry (fixed; phase indexing depends on it).
// 1024 blocks x 256 thr = 262144 threads = 4096 waves; 4 blocks/CU.
#define GBLK 1024
#define BLK  256

// RESHAPE SEMANTICS (the R3/R4 bug, fixed in R5): edge_proj.reshape(H,E) on a
// row-major [E,4] buffer is axis-scrambled: edge_proj[h,e] = flat[h*65536+e].
// Softmax group h = flat range [h*65536,(h+1)*65536). Always index flat.
// Same for node_proj[h,d,f] = npflat[h*262144 + d*64 + f].

struct Args {
    const float* X;  const float* Xe;
    const int* src;  const int* dst;
    const float* Wn; const float* bn;
    const float* We; const float* be;
    float* out;
    float* nproj;        // [4096*256] flat
    float* ep;           // [65536*4] flat, PRE-EXPONENTIATED matrix elements
    float* partials;     // [1024] per-wave scalar exp-sums (wave w -> group w>>8)
    float* stats;        // [4] = 0.25 / sum_h
    unsigned long long* tbl;  // [TBL_SIZE] dedup hash
};

__device__ __forceinline__ unsigned hash_key(unsigned key) {
    return (key * 2654435761u) >> (32 - TBL_BITS);
}

// ---------------------------------------------------------------------------
// P0: zero out+tbl; node GEMM (4 rows/thread, Wn column reused 4x);
//     edge GEMM -> exp (no max-sub: |logit*0.25| <= ~1.3, shift-invariant)
//     + per-wave scalar sums in FLAT order (group h = wave>>8).
// ---------------------------------------------------------------------------
__device__ __forceinline__ void phase0(const Args& A, int tid) {
    {   // zero d_out (65536 f4) + hash table (131072 f4)
        const float4 z = make_float4(0.f, 0.f, 0.f, 0.f);
        if (tid < 65536)       ((float4*)A.out)[tid] = z;
        else if (tid < 196608) ((float4*)A.tbl)[tid - 65536] = z;
    }
    {   // node GEMM: thread -> column c, rows n0, n0+1024, n0+2048, n0+3072
        const int c  = tid & 255;
        const int n0 = tid >> 8;  // block-uniform
        const float b = A.bn[c];
        float a0 = b, a1 = b, a2 = b, a3 = b;
        const float* Wc = A.Wn + c;
#pragma unroll 8
        for (int k = 0; k < 64; ++k) {
            const float w = Wc[k * 256];
            a0 = fmaf(A.X[(n0       ) * 64 + k], w, a0);
            a1 = fmaf(A.X[(n0 + 1024) * 64 + k], w, a1);
            a2 = fmaf(A.X[(n0 + 2048) * 64 + k], w, a2);
            a3 = fmaf(A.X[(n0 + 3072) * 64 + k], w, a3);
        }
        A.nproj[(n0       ) * 256 + c] = a0;
        A.nproj[(n0 + 1024) * 256 + c] = a1;
        A.nproj[(n0 + 2048) * 256 + c] = a2;
        A.nproj[(n0 + 3072) * 256 + c] = a3;
    }
    if (tid < 65536) {  // edge GEMM row `tid` + exp + per-wave flat-order sum
        const float4* xi = (const float4*)(A.Xe + (size_t)tid * 16);
        float x[16];
        float4 v;
        v = xi[0]; x[0]=v.x;  x[1]=v.y;  x[2]=v.z;  x[3]=v.w;
        v = xi[1]; x[4]=v.x;  x[5]=v.y;  x[6]=v.z;  x[7]=v.w;
        v = xi[2]; x[8]=v.x;  x[9]=v.y;  x[10]=v.z; x[11]=v.w;
        v = xi[3]; x[12]=v.x; x[13]=v.y; x[14]=v.z; x[15]=v.w;
        float a0 = A.be[0], a1 = A.be[1], a2 = A.be[2], a3 = A.be[3];
#pragma unroll
        for (int k = 0; k < 16; ++k) {
            a0 = fmaf(x[k], A.We[k * 4 + 0], a0);
            a1 = fmaf(x[k], A.We[k * 4 + 1], a1);
            a2 = fmaf(x[k], A.We[k * 4 + 2], a2);
            a3 = fmaf(x[k], A.We[k * 4 + 3], a3);
        }
        const float e0 = expf(a0 * 0.25f), e1 = expf(a1 * 0.25f);
        const float e2 = expf(a2 * 0.25f), e3 = expf(a3 * 0.25f);
        ((float4*)A.ep)[tid] = make_float4(e0, e1, e2, e3);
        // Wave w covers flat [256w, 256w+256), inside group h = w>>8.
        float s = e0 + e1 + e2 + e3;
#pragma unroll
        for (int off = 32; off > 0; off >>= 1) s += __shfl_xor(s, off);
        if ((tid & 63) == 0) A.partials[tid >> 6] = s;
    }
}

// ---------------------------------------------------------------------------
// P1: hash-insert (last-occurring edge wins via atomicMax on packed (tag,e)).
// ---------------------------------------------------------------------------
__device__ __forceinline__ void phase1(const Args& A, int tid) {
    if (tid >= 65536) return;
    const unsigned key = ((unsigned)A.src[tid] << 12) | (unsigned)A.dst[tid];
    const unsigned long long tag  = (unsigned long long)(key + 1u);
    const unsigned long long pack = (tag << 24) | (unsigned long long)tid;
    unsigned i = hash_key(key);
    while (true) {
        unsigned long long cur = A.tbl[i];
        if (cur == 0ull) {
            unsigned long long old = atomicCAS(&A.tbl[i], 0ull, pack);
            if (old == 0ull) return;
            cur = old;
        }
        if ((cur >> 24) == tag) { atomicMax(&A.tbl[i], pack); return; }
        i = (i + 1u) & TBL_MASK;
    }
}

// P1b (block 0 only): stats[h] = 0.25 / sum(partials[256h .. 256h+256)).
__device__ __forceinline__ void phase1b(const Args& A) {
    __shared__ float4 red[256];
    const int t = threadIdx.x;
    red[t] = make_float4(A.partials[t], A.partials[256 + t],
                         A.partials[512 + t], A.partials[768 + t]);
    __syncthreads();
    for (int s = 128; s > 0; s >>= 1) {
        if (t < s) {
            red[t].x += red[t + s].x; red[t].y += red[t + s].y;
            red[t].z += red[t + s].z; red[t].w += red[t + s].w;
        }
        __syncthreads();
    }
    if (t == 0) {
        A.stats[0] = 0.25f / red[0].x;  // fold head-mean 1/4 into 1/sum
        A.stats[1] = 0.25f / red[0].y;
        A.stats[2] = 0.25f / red[0].z;
        A.stats[3] = 0.25f / red[0].w;
    }
}

// ---------------------------------------------------------------------------
// P2: message passing. Wave per edge-group (lane = feature), 16 edges/wave,
// processed 4 at a time with independent first-probe loads in flight
// (hash probe is a ~200cy L2 dependent chain; 4-wide overlaps it).
// attn[h,e] = ep_flat[h*65536+e] * stats[h];
// out[s,f] += sum_h attn[h,e] * npflat[h*262144 + d*64 + f]  (winner only)
// ---------------------------------------------------------------------------
__device__ __forceinline__ void phase2(const Args& A, int tid) {
    const int w = tid >> 6;   // 0..4095
    const int f = tid & 63;
    const float r0 = A.stats[0], r1 = A.stats[1];
    const float r2 = A.stats[2], r3 = A.stats[3];
#pragma unroll
    for (int i = 0; i < 16; i += 4) {
        int e[4], s[4], d[4];
        unsigned long long tag[4], cur[4];
        unsigned idx[4];
#pragma unroll
        for (int j = 0; j < 4; ++j) {
            e[j] = w * 16 + i + j;
            s[j] = A.src[e[j]];
            d[j] = A.dst[e[j]];
            const unsigned key = ((unsigned)s[j] << 12) | (unsigned)d[j];
            tag[j] = (unsigned long long)(key + 1u);
            idx[j] = hash_key(key);
        }
#pragma unroll
        for (int j = 0; j < 4; ++j) cur[j] = A.tbl[idx[j]];  // 4 loads in flight
#pragma unroll
        for (int j = 0; j < 4; ++j)
            while ((cur[j] >> 24) != tag[j]) {               // rare collision fixup
                idx[j] = (idx[j] + 1u) & TBL_MASK;
                cur[j] = A.tbl[idx[j]];
            }
#pragma unroll
        for (int j = 0; j < 4; ++j) {
            if ((unsigned)(cur[j] & 0xFFFFFFull) != (unsigned)e[j]) continue;
            const float a0 = A.ep[e[j]];
            const float a1 = A.ep[65536 + e[j]];
            const float a2 = A.ep[131072 + e[j]];
            const float a3 = A.ep[196608 + e[j]];
            const int base = d[j] * 64 + f;
            float v = a0 * r0 * A.nproj[base];
            v = fmaf(a1 * r1, A.nproj[base + 262144], v);
            v = fmaf(a2 * r2, A.nproj[base + 524288], v);
            v = fmaf(a3 * r3, A.nproj[base + 786432], v);
            unsafeAtomicAdd(&A.out[s[j] * 64 + f], v);  // native global_atomic_add_f32
        }
    }
}

// ---------------------------------------------------------------------------
__global__ __launch_bounds__(BLK, 4) void k_fused(Args A) {
    cg::grid_group g = cg::this_grid();
    const int tid = blockIdx.x * BLK + threadIdx.x;
    phase0(A, tid);
    g.sync();
    phase1(A, tid);
    if (blockIdx.x == 0) phase1b(A);
    g.sync();
    phase2(A, tid);
}

// Fallback path (3 plain dispatches) if cooperative launch is rejected.
__global__ __launch_bounds__(BLK, 4) void k_p0(Args A) {
    phase0(A, blockIdx.x * BLK + threadIdx.x);
}
__global__ __launch_bounds__(BLK, 4) void k_p1(Args A) {
    phase1(A, blockIdx.x * BLK + threadIdx.x);
    if (blockIdx.x == 0) phase1b(A);
}
__global__ __launch_bounds__(BLK, 4) void k_p2(Args A) {
    phase2(A, blockIdx.x * BLK + threadIdx.x);
}

// ---------------------------------------------------------------------------
extern "C" void kernel_launch(void* const* d_in, const int* in_sizes, int n_in,
                              void* d_out, int out_size, void* d_ws, size_t ws_size,
                              hipStream_t stream) {
    Args A;
    A.X   = (const float*)d_in[0];
    A.Xe  = (const float*)d_in[1];
    A.src = (const int*)d_in[2];
    A.dst = (const int*)d_in[3];
    A.Wn  = (const float*)d_in[4];
    A.bn  = (const float*)d_in[5];
    A.We  = (const float*)d_in[6];
    A.be  = (const float*)d_in[7];
    A.out = (float*)d_out;
    char* ws     = (char*)d_ws;
    A.nproj      = (float*)ws;                                     // 4 MB
    A.ep         = (float*)(ws + 4u * 1024u * 1024u);              // 1 MB
    A.partials   = (float*)(ws + 5u * 1024u * 1024u);              // 4 KB
    A.stats      = (float*)(ws + 5u * 1024u * 1024u + 16384u);     // 16 B
    A.tbl        = (unsigned long long*)(ws + 6u * 1024u * 1024u); // 2 MB

    void* kargs[] = { &A };
    hipError_t err = hipLaunchCooperativeKernel((const void*)k_fused,
                                                dim3(GBLK), dim3(BLK),
                                                kargs, 0, stream);
    if (err != hipSuccess) {
        k_p0<<<GBLK, BLK, 0, stream>>>(A);
        k_p1<<<GBLK, BLK, 0, stream>>>(A);
        k_p2<<<GBLK, BLK, 0, stream>>>(A);
    }
}

// Round 7
// 53.376 us; speedup vs baseline: 5.5586x; 5.5586x over previous
//
#include <hip/hip_runtime.h>

#define TBL_BITS 18
#define TBL_SIZE (1u << TBL_BITS)
#define TBL_MASK (TBL_SIZE - 1u)

// Grid geometry (fixed; phase indexing depends on it).
// 1024 blocks x 256 thr = 262144 threads = 4096 waves.
#define GBLK 1024
#define BLK  256

// RESHAPE SEMANTICS: edge_proj.reshape(H,E) on a row-major [E,4] buffer is
// axis-scrambled: edge_proj[h,e] = flat[h*65536+e]. Softmax group h = flat
// range [h*65536,(h+1)*65536). Always index flat buffers directly.
// Same for node_proj[h,d,f] = npflat[h*262144 + d*64 + f].
//
// NOTE (R6): cooperative grid.sync() cost ~230 us extra on this 8-XCD chip
// (device-scope fence + cross-XCD barrier spin defeat L2). Plain dispatch
// boundaries (~1.5 us each) are strictly better here.

struct Args {
    const float* X;  const float* Xe;
    const int* src;  const int* dst;
    const float* Wn; const float* bn;
    const float* We; const float* be;
    float* out;
    float* nproj;        // [4096*256] flat
    float* ep;           // [65536*4] flat, PRE-EXPONENTIATED matrix elements
    float* partials;     // [1024] per-wave scalar exp-sums (wave w -> group w>>8)
    float* stats;        // [4] = 0.25 / sum_h
    unsigned long long* tbl;  // [TBL_SIZE] dedup hash
};

__device__ __forceinline__ unsigned hash_key(unsigned key) {
    return (key * 2654435761u) >> (32 - TBL_BITS);
}

// ---------------------------------------------------------------------------
// K0: zero out+tbl; node GEMM (4 rows/thread, Wn column reused 4x);
//     edge GEMM -> exp (no max-sub: |logit*0.25| <= ~1.3, shift-invariant)
//     + per-wave scalar sums in FLAT order (group h = wave>>8).
// ---------------------------------------------------------------------------
__global__ __launch_bounds__(BLK, 4) void k_p0(Args A) {
    const int tid = blockIdx.x * BLK + threadIdx.x;
    {   // zero d_out (65536 f4) + hash table (131072 f4)
        const float4 z = make_float4(0.f, 0.f, 0.f, 0.f);
        if (tid < 65536)       ((float4*)A.out)[tid] = z;
        else if (tid < 196608) ((float4*)A.tbl)[tid - 65536] = z;
    }
    {   // node GEMM: thread -> column c, rows n0, n0+1024, n0+2048, n0+3072
        const int c  = tid & 255;
        const int n0 = tid >> 8;  // == blockIdx.x, wave-uniform
        const float b = A.bn[c];
        float a0 = b, a1 = b, a2 = b, a3 = b;
        const float* Wc = A.Wn + c;
#pragma unroll 8
        for (int k = 0; k < 64; ++k) {
            const float w = Wc[k * 256];
            a0 = fmaf(A.X[(n0       ) * 64 + k], w, a0);
            a1 = fmaf(A.X[(n0 + 1024) * 64 + k], w, a1);
            a2 = fmaf(A.X[(n0 + 2048) * 64 + k], w, a2);
            a3 = fmaf(A.X[(n0 + 3072) * 64 + k], w, a3);
        }
        A.nproj[(n0       ) * 256 + c] = a0;
        A.nproj[(n0 + 1024) * 256 + c] = a1;
        A.nproj[(n0 + 2048) * 256 + c] = a2;
        A.nproj[(n0 + 3072) * 256 + c] = a3;
    }
    if (tid < 65536) {  // edge GEMM row `tid` + exp + per-wave flat-order sum
        const float4* xi = (const float4*)(A.Xe + (size_t)tid * 16);
        float x[16];
        float4 v;
        v = xi[0]; x[0]=v.x;  x[1]=v.y;  x[2]=v.z;  x[3]=v.w;
        v = xi[1]; x[4]=v.x;  x[5]=v.y;  x[6]=v.z;  x[7]=v.w;
        v = xi[2]; x[8]=v.x;  x[9]=v.y;  x[10]=v.z; x[11]=v.w;
        v = xi[3]; x[12]=v.x; x[13]=v.y; x[14]=v.z; x[15]=v.w;
        float a0 = A.be[0], a1 = A.be[1], a2 = A.be[2], a3 = A.be[3];
#pragma unroll
        for (int k = 0; k < 16; ++k) {
            a0 = fmaf(x[k], A.We[k * 4 + 0], a0);
            a1 = fmaf(x[k], A.We[k * 4 + 1], a1);
            a2 = fmaf(x[k], A.We[k * 4 + 2], a2);
            a3 = fmaf(x[k], A.We[k * 4 + 3], a3);
        }
        const float e0 = expf(a0 * 0.25f), e1 = expf(a1 * 0.25f);
        const float e2 = expf(a2 * 0.25f), e3 = expf(a3 * 0.25f);
        ((float4*)A.ep)[tid] = make_float4(e0, e1, e2, e3);
        // Wave w covers flat [256w, 256w+256), inside group h = w>>8.
        float s = e0 + e1 + e2 + e3;
#pragma unroll
        for (int off = 32; off > 0; off >>= 1) s += __shfl_xor(s, off);
        if ((tid & 63) == 0) A.partials[tid >> 6] = s;
    }
}

// ---------------------------------------------------------------------------
// K1: hash-insert (last-occurring edge wins via atomicMax on packed (tag,e));
//     block 0 reduces partials: stats[h] = 0.25 / sum(partials[256h..256h+256)).
// ---------------------------------------------------------------------------
__global__ __launch_bounds__(BLK, 4) void k_p1(Args A) {
    const int tid = blockIdx.x * BLK + threadIdx.x;
    if (tid < 65536) {
        const unsigned key = ((unsigned)A.src[tid] << 12) | (unsigned)A.dst[tid];
        const unsigned long long tag  = (unsigned long long)(key + 1u);
        const unsigned long long pack = (tag << 24) | (unsigned long long)tid;
        unsigned i = hash_key(key);
        while (true) {
            unsigned long long cur = A.tbl[i];
            if (cur == 0ull) {
                unsigned long long old = atomicCAS(&A.tbl[i], 0ull, pack);
                if (old == 0ull) break;
                cur = old;
            }
            if ((cur >> 24) == tag) {
                atomicMax(&A.tbl[i], pack);
                break;
            }
            i = (i + 1u) & TBL_MASK;
        }
    }
    if (blockIdx.x == 0) {
        __shared__ float4 red[256];
        const int t = threadIdx.x;
        red[t] = make_float4(A.partials[t], A.partials[256 + t],
                             A.partials[512 + t], A.partials[768 + t]);
        __syncthreads();
        for (int s = 128; s > 0; s >>= 1) {
            if (t < s) {
                red[t].x += red[t + s].x; red[t].y += red[t + s].y;
                red[t].z += red[t + s].z; red[t].w += red[t + s].w;
            }
            __syncthreads();
        }
        if (t == 0) {
            A.stats[0] = 0.25f / red[0].x;  // fold head-mean 1/4 into 1/sum
            A.stats[1] = 0.25f / red[0].y;
            A.stats[2] = 0.25f / red[0].z;
            A.stats[3] = 0.25f / red[0].w;
        }
    }
}

// ---------------------------------------------------------------------------
// K2: message passing. Wave per edge-group (lane = feature), 16 edges/wave,
// processed 4 at a time: 4 independent first-probe tbl loads issued back-to-
// back overlap the ~200cy L2 dependent chains. Winner edges accumulate with
// native f32 atomics (unsafeAtomicAdd -> global_atomic_add_f32; proven
// bit-identical to the CAS path in R3/R4).
// attn[h,e] = ep_flat[h*65536+e] * stats[h];
// out[s,f] += sum_h attn[h,e] * npflat[h*262144 + d*64 + f]  (winner only)
// ---------------------------------------------------------------------------
__global__ __launch_bounds__(BLK, 4) void k_p2(Args A) {
    const int tid = blockIdx.x * BLK + threadIdx.x;
    const int w = tid >> 6;   // 0..4095
    const int f = tid & 63;
    const float r0 = A.stats[0], r1 = A.stats[1];
    const float r2 = A.stats[2], r3 = A.stats[3];
#pragma unroll
    for (int i = 0; i < 16; i += 4) {
        int e[4], s[4], d[4];
        unsigned long long tag[4], cur[4];
        unsigned idx[4];
#pragma unroll
        for (int j = 0; j < 4; ++j) {
            e[j] = w * 16 + i + j;
            s[j] = A.src[e[j]];
            d[j] = A.dst[e[j]];
            const unsigned key = ((unsigned)s[j] << 12) | (unsigned)d[j];
            tag[j] = (unsigned long long)(key + 1u);
            idx[j] = hash_key(key);
        }
#pragma unroll
        for (int j = 0; j < 4; ++j) cur[j] = A.tbl[idx[j]];  // 4 loads in flight
#pragma unroll
        for (int j = 0; j < 4; ++j)
            while ((cur[j] >> 24) != tag[j]) {               // rare collision fixup
                idx[j] = (idx[j] + 1u) & TBL_MASK;
                cur[j] = A.tbl[idx[j]];
            }
#pragma unroll
        for (int j = 0; j < 4; ++j) {
            if ((unsigned)(cur[j] & 0xFFFFFFull) != (unsigned)e[j]) continue;
            const float a0 = A.ep[e[j]];
            const float a1 = A.ep[65536 + e[j]];
            const float a2 = A.ep[131072 + e[j]];
            const float a3 = A.ep[196608 + e[j]];
            const int base = d[j] * 64 + f;
            float v = a0 * r0 * A.nproj[base];
            v = fmaf(a1 * r1, A.nproj[base + 262144], v);
            v = fmaf(a2 * r2, A.nproj[base + 524288], v);
            v = fmaf(a3 * r3, A.nproj[base + 786432], v);
            unsafeAtomicAdd(&A.out[s[j] * 64 + f], v);
        }
    }
}

// ---------------------------------------------------------------------------
extern "C" void kernel_launch(void* const* d_in, const int* in_sizes, int n_in,
                              void* d_out, int out_size, void* d_ws, size_t ws_size,
                              hipStream_t stream) {
    Args A;
    A.X   = (const float*)d_in[0];
    A.Xe  = (const float*)d_in[1];
    A.src = (const int*)d_in[2];
    A.dst = (const int*)d_in[3];
    A.Wn  = (const float*)d_in[4];
    A.bn  = (const float*)d_in[5];
    A.We  = (const float*)d_in[6];
    A.be  = (const float*)d_in[7];
    A.out = (float*)d_out;
    char* ws     = (char*)d_ws;
    A.nproj      = (float*)ws;                                     // 4 MB
    A.ep         = (float*)(ws + 4u * 1024u * 1024u);              // 1 MB
    A.partials   = (float*)(ws + 5u * 1024u * 1024u);              // 4 KB
    A.stats      = (float*)(ws + 5u * 1024u * 1024u + 16384u);     // 16 B
    A.tbl        = (unsigned long long*)(ws + 6u * 1024u * 1024u); // 2 MB

    k_p0<<<GBLK, BLK, 0, stream>>>(A);
    k_p1<<<GBLK, BLK, 0, stream>>>(A);
    k_p2<<<GBLK, BLK, 0, stream>>>(A);
}

// Round 8
// 52.556 us; speedup vs baseline: 5.6454x; 1.0156x over previous
//
#include <hip/hip_runtime.h>

#define TBL_BITS 18
#define TBL_SIZE (1u << TBL_BITS)
#define TBL_MASK (TBL_SIZE - 1u)

// Grid geometry (fixed; phase indexing depends on it).
#define GBLK 1024          // k_p0 grid: 262144 threads
#define BLK  256

// RESHAPE SEMANTICS: edge_proj.reshape(H,E) on a row-major [E,4] buffer is
// axis-scrambled: edge_proj[h,e] = flat[h*65536+e]. Softmax group h = flat
// range [h*65536,(h+1)*65536). Always index flat buffers directly.
// Same for node_proj[h,d,f] = npflat[h*262144 + d*64 + f].
//
// NOTE (R6): cooperative grid.sync() cost ~230 us extra on this 8-XCD chip
// (device-scope fence + cross-XCD barrier spin defeat L2). Plain dispatch
// boundaries (~1.5 us each) are strictly better here.
// NOTE (R7): native f32 atomics (unsafeAtomicAdd) + 4-wide probe ILP in P2
// were worth -7.4 us vs CAS-loop atomicAdd + serial probes.

struct Args {
    const float* X;  const float* Xe;
    const int* src;  const int* dst;
    const float* Wn; const float* bn;
    const float* We; const float* be;
    float* out;
    float* nproj;        // [4096*256] flat
    float* ep;           // [65536*4] flat, PRE-EXPONENTIATED matrix elements
    float* partials;     // [1024] per-wave scalar exp-sums (wave w -> group w>>8)
    float* stats;        // [4] = 0.25 / sum_h
    unsigned long long* tbl;  // [TBL_SIZE] dedup hash
};

__device__ __forceinline__ unsigned hash_key(unsigned key) {
    return (key * 2654435761u) >> (32 - TBL_BITS);
}

// ---------------------------------------------------------------------------
// K0: zero out+tbl; node GEMM — 8 rows/thread (512 row-groups, tids<131072)
//     so each Wn element is read 512x (32 MB L2 traffic, was 64 MB at 4 rows);
//     edge GEMM -> exp (no max-sub: |logit*0.25| <= ~1.3, shift-invariant)
//     + per-wave scalar sums in FLAT order (group h = wave>>8).
// ---------------------------------------------------------------------------
__global__ __launch_bounds__(BLK, 4) void k_p0(Args A) {
    const int tid = blockIdx.x * BLK + threadIdx.x;
    {   // zero d_out (65536 f4) + hash table (131072 f4)
        const float4 z = make_float4(0.f, 0.f, 0.f, 0.f);
        if (tid < 65536)       ((float4*)A.out)[tid] = z;
        else if (tid < 196608) ((float4*)A.tbl)[tid - 65536] = z;
    }
    if (tid < 131072) {  // node GEMM: col c, rows g+512r (r=0..7)
        const int c = tid & 255;
        const int g = tid >> 8;  // 0..511, block-uniform
        const float b = A.bn[c];
        float acc[8];
#pragma unroll
        for (int r = 0; r < 8; ++r) acc[r] = b;
        const float* Wc = A.Wn + c;
#pragma unroll 8
        for (int k = 0; k < 64; ++k) {
            const float w = Wc[k * 256];
#pragma unroll
            for (int r = 0; r < 8; ++r)
                acc[r] = fmaf(A.X[(g + 512 * r) * 64 + k], w, acc[r]);
        }
#pragma unroll
        for (int r = 0; r < 8; ++r)
            A.nproj[(g + 512 * r) * 256 + c] = acc[r];
    }
    if (tid < 65536) {  // edge GEMM row `tid` + exp + per-wave flat-order sum
        const float4* xi = (const float4*)(A.Xe + (size_t)tid * 16);
        float x[16];
        float4 v;
        v = xi[0]; x[0]=v.x;  x[1]=v.y;  x[2]=v.z;  x[3]=v.w;
        v = xi[1]; x[4]=v.x;  x[5]=v.y;  x[6]=v.z;  x[7]=v.w;
        v = xi[2]; x[8]=v.x;  x[9]=v.y;  x[10]=v.z; x[11]=v.w;
        v = xi[3]; x[12]=v.x; x[13]=v.y; x[14]=v.z; x[15]=v.w;
        float a0 = A.be[0], a1 = A.be[1], a2 = A.be[2], a3 = A.be[3];
#pragma unroll
        for (int k = 0; k < 16; ++k) {
            a0 = fmaf(x[k], A.We[k * 4 + 0], a0);
            a1 = fmaf(x[k], A.We[k * 4 + 1], a1);
            a2 = fmaf(x[k], A.We[k * 4 + 2], a2);
            a3 = fmaf(x[k], A.We[k * 4 + 3], a3);
        }
        const float e0 = expf(a0 * 0.25f), e1 = expf(a1 * 0.25f);
        const float e2 = expf(a2 * 0.25f), e3 = expf(a3 * 0.25f);
        ((float4*)A.ep)[tid] = make_float4(e0, e1, e2, e3);
        // Wave w covers flat [256w, 256w+256), inside group h = w>>8.
        float s = e0 + e1 + e2 + e3;
#pragma unroll
        for (int off = 32; off > 0; off >>= 1) s += __shfl_xor(s, off);
        if ((tid & 63) == 0) A.partials[tid >> 6] = s;
    }
}

// ---------------------------------------------------------------------------
// K1 (256 blocks): hash-insert (last edge wins via atomicMax on (tag,e));
//     block 0 reduces partials: stats[h] = 0.25 / sum(partials[256h..256h+256)).
// ---------------------------------------------------------------------------
__global__ __launch_bounds__(BLK, 4) void k_p1(Args A) {
    const int tid = blockIdx.x * BLK + threadIdx.x;  // 0..65535
    {
        const unsigned key = ((unsigned)A.src[tid] << 12) | (unsigned)A.dst[tid];
        const unsigned long long tag  = (unsigned long long)(key + 1u);
        const unsigned long long pack = (tag << 24) | (unsigned long long)tid;
        unsigned i = hash_key(key);
        while (true) {
            unsigned long long cur = A.tbl[i];
            if (cur == 0ull) {
                unsigned long long old = atomicCAS(&A.tbl[i], 0ull, pack);
                if (old == 0ull) break;
                cur = old;
            }
            if ((cur >> 24) == tag) {
                atomicMax(&A.tbl[i], pack);
                break;
            }
            i = (i + 1u) & TBL_MASK;
        }
    }
    if (blockIdx.x == 0) {
        __shared__ float4 red[256];
        const int t = threadIdx.x;
        red[t] = make_float4(A.partials[t], A.partials[256 + t],
                             A.partials[512 + t], A.partials[768 + t]);
        __syncthreads();
        for (int s = 128; s > 0; s >>= 1) {
            if (t < s) {
                red[t].x += red[t + s].x; red[t].y += red[t + s].y;
                red[t].z += red[t + s].z; red[t].w += red[t + s].w;
            }
            __syncthreads();
        }
        if (t == 0) {
            A.stats[0] = 0.25f / red[0].x;  // fold head-mean 1/4 into 1/sum
            A.stats[1] = 0.25f / red[0].y;
            A.stats[2] = 0.25f / red[0].z;
            A.stats[3] = 0.25f / red[0].w;
        }
    }
}

// ---------------------------------------------------------------------------
// K2 (2048 blocks): message passing. Wave per edge-group (lane = feature),
// 8 edges/wave in two 4-wide batches (independent first-probe loads overlap
// the ~200cy L2 chains); 8192 waves for 2x memory-level parallelism vs R7.
// attn[h,e] = ep_flat[h*65536+e] * stats[h];
// out[s,f] += sum_h attn[h,e] * npflat[h*262144 + d*64 + f]  (winner only)
// ---------------------------------------------------------------------------
__global__ __launch_bounds__(BLK, 4) void k_p2(Args A) {
    const int tid = blockIdx.x * BLK + threadIdx.x;
    const int w = tid >> 6;   // 0..8191
    const int f = tid & 63;
    const float r0 = A.stats[0], r1 = A.stats[1];
    const float r2 = A.stats[2], r3 = A.stats[3];
#pragma unroll
    for (int i = 0; i < 8; i += 4) {
        int e[4], s[4], d[4];
        unsigned long long tag[4], cur[4];
        unsigned idx[4];
#pragma unroll
        for (int j = 0; j < 4; ++j) {
            e[j] = w * 8 + i + j;
            s[j] = A.src[e[j]];
            d[j] = A.dst[e[j]];
            const unsigned key = ((unsigned)s[j] << 12) | (unsigned)d[j];
            tag[j] = (unsigned long long)(key + 1u);
            idx[j] = hash_key(key);
        }
#pragma unroll
        for (int j = 0; j < 4; ++j) cur[j] = A.tbl[idx[j]];  // 4 loads in flight
#pragma unroll
        for (int j = 0; j < 4; ++j)
            while ((cur[j] >> 24) != tag[j]) {               // rare collision fixup
                idx[j] = (idx[j] + 1u) & TBL_MASK;
                cur[j] = A.tbl[idx[j]];
            }
#pragma unroll
        for (int j = 0; j < 4; ++j) {
            if ((unsigned)(cur[j] & 0xFFFFFFull) != (unsigned)e[j]) continue;
            const float a0 = A.ep[e[j]];
            const float a1 = A.ep[65536 + e[j]];
            const float a2 = A.ep[131072 + e[j]];
            const float a3 = A.ep[196608 + e[j]];
            const int base = d[j] * 64 + f;
            float v = a0 * r0 * A.nproj[base];
            v = fmaf(a1 * r1, A.nproj[base + 262144], v);
            v = fmaf(a2 * r2, A.nproj[base + 524288], v);
            v = fmaf(a3 * r3, A.nproj[base + 786432], v);
            unsafeAtomicAdd(&A.out[s[j] * 64 + f], v);
        }
    }
}

// ---------------------------------------------------------------------------
extern "C" void kernel_launch(void* const* d_in, const int* in_sizes, int n_in,
                              void* d_out, int out_size, void* d_ws, size_t ws_size,
                              hipStream_t stream) {
    Args A;
    A.X   = (const float*)d_in[0];
    A.Xe  = (const float*)d_in[1];
    A.src = (const int*)d_in[2];
    A.dst = (const int*)d_in[3];
    A.Wn  = (const float*)d_in[4];
    A.bn  = (const float*)d_in[5];
    A.We  = (const float*)d_in[6];
    A.be  = (const float*)d_in[7];
    A.out = (float*)d_out;
    char* ws     = (char*)d_ws;
    A.nproj      = (float*)ws;                                     // 4 MB
    A.ep         = (float*)(ws + 4u * 1024u * 1024u);              // 1 MB
    A.partials   = (float*)(ws + 5u * 1024u * 1024u);              // 4 KB
    A.stats      = (float*)(ws + 5u * 1024u * 1024u + 16384u);     // 16 B
    A.tbl        = (unsigned long long*)(ws + 6u * 1024u * 1024u); // 2 MB

    k_p0<<<GBLK, BLK, 0, stream>>>(A);
    k_p1<<<256, BLK, 0, stream>>>(A);
    k_p2<<<2048, BLK, 0, stream>>>(A);
}

// Round 9
// 46.561 us; speedup vs baseline: 6.3722x; 1.1288x over previous
//
#include <hip/hip_runtime.h>

#define TBL_BITS 18
#define TBL_SIZE (1u << TBL_BITS)
#define TBL_MASK (TBL_SIZE - 1u)

#define GBLK 1024          // k_a grid: 262144 threads
#define BLK  256

// RESHAPE SEMANTICS: edge_proj.reshape(H,E) on a row-major [E,4] buffer is
// axis-scrambled: edge_proj[h,e] = flat[h*65536+e]. Softmax group h = flat
// range [h*65536,(h+1)*65536). Always index flat buffers directly.
// Same for node_proj[h,d,f] = npflat[h*262144 + d*64 + f].
//
// NOTE (R6): cooperative grid.sync() costs ~230 us on this 8-XCD chip. Plain
// dispatch boundaries (~1.5 us) are strictly better.
// NOTE (R7): native f32 atomics (unsafeAtomicAdd) + probe ILP: -7.4 us.
// NOTE (R9): single-pass dedup: atomicMax claims winner; new winner adds
// (ep[e]-ep[old])*r_h so the superseded contribution cancels. 3 -> 2 dispatches.

struct Args {
    const float* X;  const float* Xe;
    const int* src;  const int* dst;
    const float* Wn; const float* bn;
    const float* We; const float* be;
    float* out;
    float* nproj;        // [4096*256] flat
    float* ep;           // [65536*4] flat, PRE-EXPONENTIATED matrix elements
    float* partials;     // [1024] per-wave scalar exp-sums (wave w -> group w>>8)
    unsigned long long* tbl;  // [TBL_SIZE] dedup hash
};

__device__ __forceinline__ unsigned hash_key(unsigned key) {
    return (key * 2654435761u) >> (32 - TBL_BITS);
}

// ---------------------------------------------------------------------------
// K_A: zero out+tbl; node GEMM (8 rows/thread, Wn element read 512x);
//      edge GEMM -> exp (no max-sub: |logit*0.25| <= ~1.3, shift-invariant)
//      + per-wave scalar sums in FLAT order (group h = wave>>8).
// ---------------------------------------------------------------------------
__global__ __launch_bounds__(BLK, 4) void k_a(Args A) {
    const int tid = blockIdx.x * BLK + threadIdx.x;
    {   // zero d_out (65536 f4) + hash table (131072 f4)
        const float4 z = make_float4(0.f, 0.f, 0.f, 0.f);
        if (tid < 65536)       ((float4*)A.out)[tid] = z;
        else if (tid < 196608) ((float4*)A.tbl)[tid - 65536] = z;
    }
    if (tid < 131072) {  // node GEMM: col c, rows g+512r (r=0..7)
        const int c = tid & 255;
        const int g = tid >> 8;  // 0..511, block-uniform
        const float b = A.bn[c];
        float acc[8];
#pragma unroll
        for (int r = 0; r < 8; ++r) acc[r] = b;
        const float* Wc = A.Wn + c;
#pragma unroll 8
        for (int k = 0; k < 64; ++k) {
            const float w = Wc[k * 256];
#pragma unroll
            for (int r = 0; r < 8; ++r)
                acc[r] = fmaf(A.X[(g + 512 * r) * 64 + k], w, acc[r]);
        }
#pragma unroll
        for (int r = 0; r < 8; ++r)
            A.nproj[(g + 512 * r) * 256 + c] = acc[r];
    }
    if (tid < 65536) {  // edge GEMM row `tid` + exp + per-wave flat-order sum
        const float4* xi = (const float4*)(A.Xe + (size_t)tid * 16);
        float x[16];
        float4 v;
        v = xi[0]; x[0]=v.x;  x[1]=v.y;  x[2]=v.z;  x[3]=v.w;
        v = xi[1]; x[4]=v.x;  x[5]=v.y;  x[6]=v.z;  x[7]=v.w;
        v = xi[2]; x[8]=v.x;  x[9]=v.y;  x[10]=v.z; x[11]=v.w;
        v = xi[3]; x[12]=v.x; x[13]=v.y; x[14]=v.z; x[15]=v.w;
        float a0 = A.be[0], a1 = A.be[1], a2 = A.be[2], a3 = A.be[3];
#pragma unroll
        for (int k = 0; k < 16; ++k) {
            a0 = fmaf(x[k], A.We[k * 4 + 0], a0);
            a1 = fmaf(x[k], A.We[k * 4 + 1], a1);
            a2 = fmaf(x[k], A.We[k * 4 + 2], a2);
            a3 = fmaf(x[k], A.We[k * 4 + 3], a3);
        }
        const float e0 = expf(a0 * 0.25f), e1 = expf(a1 * 0.25f);
        const float e2 = expf(a2 * 0.25f), e3 = expf(a3 * 0.25f);
        ((float4*)A.ep)[tid] = make_float4(e0, e1, e2, e3);
        // Wave w covers flat [256w, 256w+256), inside group h = w>>8.
        float s = e0 + e1 + e2 + e3;
#pragma unroll
        for (int off = 32; off > 0; off >>= 1) s += __shfl_xor(s, off);
        if ((tid & 63) == 0) A.partials[tid >> 6] = s;
    }
}

// ---------------------------------------------------------------------------
// K_B (2048 blocks): per-block stats reduce + single-pass dedup + message.
// Wave per 8 edges (lane = feature). For each 4-edge batch, lanes 0..3 run
// the claim/max loop (4 atomic chains overlap); decisions broadcast by shfl.
// Winner adds Σ_h (ep[h,e] - ep[h,old_e]) * r_h * nproj[h,d,:] so a
// superseded duplicate's contribution cancels exactly (|err| ~1e-10).
// ---------------------------------------------------------------------------
__global__ __launch_bounds__(BLK, 4) void k_b(Args A) {
    __shared__ float4 red[256];
    __shared__ float s_stats[4];
    {   // stats: r_h = 0.25 / sum(partials[256h .. 256h+256))
        const int t = threadIdx.x;
        red[t] = make_float4(A.partials[t], A.partials[256 + t],
                             A.partials[512 + t], A.partials[768 + t]);
        __syncthreads();
        for (int s = 128; s > 0; s >>= 1) {
            if (t < s) {
                red[t].x += red[t + s].x; red[t].y += red[t + s].y;
                red[t].z += red[t + s].z; red[t].w += red[t + s].w;
            }
            __syncthreads();
        }
        if (t == 0) {
            s_stats[0] = 0.25f / red[0].x;
            s_stats[1] = 0.25f / red[0].y;
            s_stats[2] = 0.25f / red[0].z;
            s_stats[3] = 0.25f / red[0].w;
        }
        __syncthreads();
    }
    const float r0 = s_stats[0], r1 = s_stats[1];
    const float r2 = s_stats[2], r3 = s_stats[3];

    const int tid  = blockIdx.x * BLK + threadIdx.x;
    const int w    = tid >> 6;   // 0..8191
    const int lane = tid & 63;   // = feature f

#pragma unroll
    for (int i = 0; i < 8; i += 4) {
        const int ebase = w * 8 + i;
        // lanes 0..3: resolve table for edge ebase+lane.
        // action: 0 = loser/skip, 1 = add (sub_e<0: plain add; else subtract old)
        int action = 0;
        int sub_e  = -1;
        if (lane < 4) {
            const int e = ebase + lane;
            const unsigned key = ((unsigned)A.src[e] << 12) | (unsigned)A.dst[e];
            const unsigned long long tag  = (unsigned long long)(key + 1u);
            const unsigned long long pack = (tag << 24) | (unsigned long long)e;
            unsigned idx = hash_key(key);
            while (true) {
                unsigned long long cur = A.tbl[idx];
                if (cur == 0ull) {
                    unsigned long long old = atomicCAS(&A.tbl[idx], 0ull, pack);
                    if (old == 0ull) { action = 1; break; }  // claimed empty slot
                    cur = old;
                }
                if ((cur >> 24) == tag) {
                    const unsigned long long old = atomicMax(&A.tbl[idx], pack);
                    if (old < pack) {            // we are the new winner
                        action = 1;
                        sub_e = (int)(old & 0xFFFFFFull);
                    }                            // else: bigger e already added
                    break;
                }
                idx = (idx + 1u) & TBL_MASK;
            }
        }
#pragma unroll
        for (int j = 0; j < 4; ++j) {
            const int act = __shfl(action, j);
            if (!act) continue;
            const int e  = ebase + j;
            const int sj = A.src[e];            // wave-uniform scalar loads
            const int dj = A.dst[e];
            const int se = __shfl(sub_e, j);
            float c0 = A.ep[e];
            float c1 = A.ep[65536 + e];
            float c2 = A.ep[131072 + e];
            float c3 = A.ep[196608 + e];
            if (se >= 0) {                      // cancel superseded duplicate
                c0 -= A.ep[se];
                c1 -= A.ep[65536 + se];
                c2 -= A.ep[131072 + se];
                c3 -= A.ep[196608 + se];
            }
            const int base = dj * 64 + lane;
            float v = c0 * r0 * A.nproj[base];
            v = fmaf(c1 * r1, A.nproj[base + 262144], v);
            v = fmaf(c2 * r2, A.nproj[base + 524288], v);
            v = fmaf(c3 * r3, A.nproj[base + 786432], v);
            unsafeAtomicAdd(&A.out[sj * 64 + lane], v);
        }
    }
}

// ---------------------------------------------------------------------------
extern "C" void kernel_launch(void* const* d_in, const int* in_sizes, int n_in,
                              void* d_out, int out_size, void* d_ws, size_t ws_size,
                              hipStream_t stream) {
    Args A;
    A.X   = (const float*)d_in[0];
    A.Xe  = (const float*)d_in[1];
    A.src = (const int*)d_in[2];
    A.dst = (const int*)d_in[3];
    A.Wn  = (const float*)d_in[4];
    A.bn  = (const float*)d_in[5];
    A.We  = (const float*)d_in[6];
    A.be  = (const float*)d_in[7];
    A.out = (float*)d_out;
    char* ws   = (char*)d_ws;
    A.nproj    = (float*)ws;                                     // 4 MB
    A.ep       = (float*)(ws + 4u * 1024u * 1024u);              // 1 MB
    A.partials = (float*)(ws + 5u * 1024u * 1024u);              // 4 KB
    A.tbl      = (unsigned long long*)(ws + 6u * 1024u * 1024u); // 2 MB

    k_a<<<GBLK, BLK, 0, stream>>>(A);
    k_b<<<2048, BLK, 0, stream>>>(A);
}